// Round 3
// baseline (2910.981 us; speedup 1.0000x reference)
//
#include <hip/hip_runtime.h>
#include <hip/hip_bf16.h>
#include <math.h>

typedef __hip_bfloat16 bf16;

// Problem constants: b=8, c=512, h=w=64 -> hw=4096, inter=256, hw2=2048
static const long QS = 2097152;  // 512*4096 per-batch q/k/v/out elems
static const long PS = 1048576;  // 256*4096 == 512*2048 per-batch phi/theta/g/yt elems
static const long SS = 4194304;  // 2048*2048 per-batch scores elems

__device__ __forceinline__ float cvt(float x) { return x; }
__device__ __forceinline__ float cvt(bf16 x) { return __bfloat162float(x); }
__device__ __forceinline__ void stc(float* p, float v) { *p = v; }
__device__ __forceinline__ void stc(bf16* p, float v) { *p = __float2bfloat16(v); }

// 64x64-tile fp32-accum GEMM: C[m][n] = sum_k A[m][k]*B[k][n]  (+ optional epilogue)
// ACOL: A stored column-major (A[m][k] at A[k*lda + m]) — used for theta^T.
// EPI:  adds fp32 residuals Eq+Ev before store.
// All pointers are per-batch (host applies batch offsets).
template <typename TA, typename TB, typename TC, bool ACOL, bool EPI>
__global__ __launch_bounds__(256) void gemm_k(
    const TA* __restrict__ A, const TB* __restrict__ B, TC* __restrict__ C,
    const float* __restrict__ Eq, const float* __restrict__ Ev,
    int K, int lda, int ldb, int ldc)
{
    __shared__ float As[16][64];  // As[k][m]
    __shared__ float Bs[16][64];  // Bs[k][n]
    const int n0 = blockIdx.x * 64;
    const int m0 = blockIdx.y * 64;
    const int tid = threadIdx.x;
    const int tx = tid & 15, ty = tid >> 4;

    float acc[4][4] = {};

    for (int k0 = 0; k0 < K; k0 += 16) {
        if constexpr (ACOL) {
            int mi = tid & 63, kb = tid >> 6;
#pragma unroll
            for (int i = 0; i < 4; ++i) {
                int kk = kb * 4 + i;
                As[kk][mi] = cvt(A[(long)(k0 + kk) * lda + (m0 + mi)]);
            }
        } else {
            int kk = tid & 15, mb = tid >> 4;
#pragma unroll
            for (int i = 0; i < 4; ++i) {
                int mm = mb + 16 * i;
                As[kk][mm] = cvt(A[(long)(m0 + mm) * lda + (k0 + kk)]);
            }
        }
        {
            int ni = tid & 63, kb = tid >> 6;
#pragma unroll
            for (int i = 0; i < 4; ++i) {
                int kk = kb * 4 + i;
                Bs[kk][ni] = cvt(B[(long)(k0 + kk) * ldb + (n0 + ni)]);
            }
        }
        __syncthreads();
#pragma unroll
        for (int kk = 0; kk < 16; ++kk) {
            float4 av = *reinterpret_cast<const float4*>(&As[kk][ty * 4]);
            float4 bv = *reinterpret_cast<const float4*>(&Bs[kk][tx * 4]);
            float a[4] = {av.x, av.y, av.z, av.w};
            float b[4] = {bv.x, bv.y, bv.z, bv.w};
#pragma unroll
            for (int i = 0; i < 4; ++i)
#pragma unroll
                for (int j = 0; j < 4; ++j)
                    acc[i][j] = fmaf(a[i], b[j], acc[i][j]);
        }
        __syncthreads();
    }

#pragma unroll
    for (int i = 0; i < 4; ++i) {
        long row = (long)(m0 + ty * 4 + i) * ldc + n0 + tx * 4;
#pragma unroll
        for (int j = 0; j < 4; ++j) {
            float r = acc[i][j];
            if constexpr (EPI) r += Eq[row + j] + Ev[row + j];
            stc(&C[row + j], r);
        }
    }
}

// Column softmax of S[2048][2048] over rows (axis n = row index), per column m.
// P1: block = 64 cols x 256-row chunk -> online (max, sumexp) partials.
template <typename TS>
__global__ __launch_bounds__(256) void softmax_p1(
    const TS* __restrict__ S, float2* __restrict__ Part)
{
    const int cx = threadIdx.x & 63;
    const int ry = threadIdx.x >> 6;
    const int m = blockIdx.x * 64 + cx;
    const int rc = blockIdx.y;

    float mx = -INFINITY, l = 0.f;
    for (int r = rc * 256 + ry; r < rc * 256 + 256; r += 4) {
        float v = cvt(S[(long)r * 2048 + m]);
        float nm = fmaxf(mx, v);
        l = l * __expf(mx - nm) + __expf(v - nm);
        mx = nm;
    }
    __shared__ float sm[4][64], sl[4][64];
    sm[ry][cx] = mx;
    sl[ry][cx] = l;
    __syncthreads();
    if (ry == 0) {
        float M = sm[0][cx], L = sl[0][cx];
#pragma unroll
        for (int i = 1; i < 4; ++i) {
            float nm = fmaxf(M, sm[i][cx]);
            L = L * __expf(M - nm) + sl[i][cx] * __expf(sm[i][cx] - nm);
            M = nm;
        }
        Part[(long)rc * 2048 + m] = make_float2(M, L);
    }
}

// P2: combine 8 chunk partials per column, then normalize this chunk in place.
template <typename TS>
__global__ __launch_bounds__(256) void softmax_p2(
    TS* __restrict__ S, const float2* __restrict__ Part)
{
    const int m0 = blockIdx.x * 64;
    const int rc = blockIdx.y;
    const int tid = threadIdx.x;

    __shared__ float Ms[64], Li[64];
    if (tid < 64) {
        float M = -INFINITY, L = 0.f;
#pragma unroll
        for (int i = 0; i < 8; ++i) {
            float2 p = Part[(long)i * 2048 + m0 + tid];
            float nm = fmaxf(M, p.x);
            L = L * __expf(M - nm) + p.y * __expf(p.x - nm);
            M = nm;
        }
        Ms[tid] = M;
        Li[tid] = 1.0f / L;
    }
    __syncthreads();
    const int cx = tid & 63, ry = tid >> 6;
    const int m = m0 + cx;
    const float M = Ms[cx], invL = Li[cx];
    for (int r = rc * 256 + ry; r < rc * 256 + 256; r += 4) {
        long idx = (long)r * 2048 + m;
        stc(&S[idx], __expf(cvt(S[idx]) - M) * invL);
    }
}

extern "C" void kernel_launch(void* const* d_in, const int* in_sizes, int n_in,
                              void* d_out, int out_size, void* d_ws, size_t ws_size,
                              hipStream_t stream)
{
    // Reference dtypes are float32 for ALL inputs and the output.
    const float* q    = (const float*)d_in[0];
    const float* kk   = (const float*)d_in[1];
    const float* v    = (const float*)d_in[2];
    const float* Wphi = (const float*)d_in[3];
    const float* Wth  = (const float*)d_in[4];
    const float* Wg   = (const float*)d_in[5];
    const float* Wm   = (const float*)d_in[6];
    float* out = (float*)d_out;
    dim3 blk(256);

    // Tier A (>= 32.1 MB): fp32 Phi/Th/G (4 MB ea) + fp32 Yt (4 MB)
    //                      + Part (128 KB) + fp32 S (16 MB)
    // Tier B (>= 18.1 MB): bf16 Phi/Th/G/S, fp32 Yt
    const size_t needA = (size_t)(3 * PS + PS + SS) * 4 + (size_t)(8 * 2048) * 8;

    if (ws_size >= needA) {
        float* Phi = (float*)d_ws;
        float* Th  = Phi + PS;
        float* G   = Th + PS;
        float* Yt  = G + PS;
        float2* Part = (float2*)(Yt + PS);
        float* S = (float*)(Part + 8L * 2048);

        for (int b = 0; b < 8; ++b) {
            // 1x1 convs: M=256, N=4096, K=512 (out viewed as [512][2048])
            gemm_k<float, float, float, false, false><<<dim3(64, 4), blk, 0, stream>>>(
                Wphi, q + b * QS, Phi, nullptr, nullptr, 512, 512, 4096, 4096);
            gemm_k<float, float, float, false, false><<<dim3(64, 4), blk, 0, stream>>>(
                Wth, kk + b * QS, Th, nullptr, nullptr, 512, 512, 4096, 4096);
            gemm_k<float, float, float, false, false><<<dim3(64, 4), blk, 0, stream>>>(
                Wg, v + b * QS, G, nullptr, nullptr, 512, 512, 4096, 4096);
            // S[n][m] = sum_c Th[c][n]*Phi[c][m]: ACOL, M=N=2048, K=512
            gemm_k<float, float, float, true, false><<<dim3(32, 32), blk, 0, stream>>>(
                Th, Phi, S, nullptr, nullptr, 512, 2048, 2048, 2048);
            softmax_p1<float><<<dim3(32, 8), blk, 0, stream>>>(S, Part);
            softmax_p2<float><<<dim3(32, 8), blk, 0, stream>>>(S, Part);
            // Yt[c][m] = sum_n G[c][n]*A[n][m]: M=512, N=2048, K=2048
            gemm_k<float, float, float, false, false><<<dim3(32, 8), blk, 0, stream>>>(
                G, S, Yt, nullptr, nullptr, 2048, 2048, 2048, 2048);
            // mask conv + residual: M=512, N=4096, K=256 (Yt viewed [256][4096])
            gemm_k<float, float, float, false, true><<<dim3(64, 8), blk, 0, stream>>>(
                Wm, Yt, out + b * QS, q + b * QS, v + b * QS, 256, 256, 4096, 4096);
        }
    } else {
        bf16* Phi = (bf16*)d_ws;
        bf16* Th  = Phi + PS;
        bf16* G   = Th + PS;
        float* Yt = (float*)(G + PS);
        float2* Part = (float2*)(Yt + PS);
        bf16* S = (bf16*)(Part + 8L * 2048);

        for (int b = 0; b < 8; ++b) {
            gemm_k<float, float, bf16, false, false><<<dim3(64, 4), blk, 0, stream>>>(
                Wphi, q + b * QS, Phi, nullptr, nullptr, 512, 512, 4096, 4096);
            gemm_k<float, float, bf16, false, false><<<dim3(64, 4), blk, 0, stream>>>(
                Wth, kk + b * QS, Th, nullptr, nullptr, 512, 512, 4096, 4096);
            gemm_k<float, float, bf16, false, false><<<dim3(64, 4), blk, 0, stream>>>(
                Wg, v + b * QS, G, nullptr, nullptr, 512, 512, 4096, 4096);
            gemm_k<bf16, bf16, bf16, true, false><<<dim3(32, 32), blk, 0, stream>>>(
                Th, Phi, S, nullptr, nullptr, 512, 2048, 2048, 2048);
            softmax_p1<bf16><<<dim3(32, 8), blk, 0, stream>>>(S, Part);
            softmax_p2<bf16><<<dim3(32, 8), blk, 0, stream>>>(S, Part);
            gemm_k<bf16, bf16, float, false, false><<<dim3(32, 8), blk, 0, stream>>>(
                G, S, Yt, nullptr, nullptr, 2048, 2048, 2048, 2048);
            gemm_k<float, float, float, false, true><<<dim3(64, 8), blk, 0, stream>>>(
                Wm, Yt, out + b * QS, q + b * QS, v + b * QS, 256, 256, 4096, 4096);
        }
    }
}

// Round 4
// 1197.198 us; speedup vs baseline: 2.4315x; 2.4315x over previous
//
#include <hip/hip_runtime.h>
#include <hip/hip_bf16.h>
#include <math.h>

typedef __hip_bfloat16 hbf16;
typedef __attribute__((ext_vector_type(8))) short short8;   // 8 bf16 (4 VGPRs)
typedef __attribute__((ext_vector_type(4))) float f32x4;

static const long QS = 2097152;  // 512*4096 per-batch q/k/v/out elems

__device__ __forceinline__ unsigned short f2bf(float f) {
    hbf16 h = __float2bfloat16(f);
    return *reinterpret_cast<unsigned short*>(&h);
}
__device__ __forceinline__ float bf2f(unsigned short u) {
    unsigned x = ((unsigned)u) << 16;
    return __uint_as_float(x);
}
__device__ __forceinline__ unsigned pk2(float a, float b) {
    return (unsigned)f2bf(a) | ((unsigned)f2bf(b) << 16);
}

// async 16-B global->LDS (wave-uniform LDS base + lane*16)
__device__ __forceinline__ void gload16(const void* g, void* l) {
    __builtin_amdgcn_global_load_lds(
        (const __attribute__((address_space(1))) void*)g,
        (__attribute__((address_space(3))) void*)l, 16, 0, 0);
}

// Stage R rows x 32 k (bf16) from global P (row0*ld + koff addressing) into Ls.
// LDS slot s of row r holds global k-chunk (s ^ (r&3))  [xor swizzle].
template <int R>
__device__ __forceinline__ void stage_direct(const short* P, int ld, int row0,
                                             long koff, short* Ls) {
    const int tid = threadIdx.x;
    const int w = tid >> 6, lane = tid & 63;
#pragma unroll
    for (int j = 0; j < R / 64; ++j) {
        int rb = j * 64 + w * 16;
        int r = rb + (lane >> 2);
        int s = lane & 3;
        int g = s ^ (r & 3);
        const short* ga = P + (long)(row0 + r) * ld + koff + g * 8;
        gload16(ga, Ls + rb * 32);
    }
}

// Stage R rows x 32 k from fp32 source X where operand[r][k] = X[(k0+k)*sld + row0+r]
// (transpose+cast in VGPRs, ds_write_b128, same xor swizzle).
template <int R>
__device__ __forceinline__ void stage_trans(const float* X, int sld, int row0,
                                            int k0, short* Ls) {
    const int tid = threadIdx.x;
    constexpr int L2R = (R == 128) ? 7 : 6;
#pragma unroll
    for (int j = 0; j < R / 64; ++j) {
        int idx = j * 256 + tid;
        int r = idx & (R - 1);
        int c = idx >> L2R;
        long base = (long)(k0 + c * 8) * sld + row0 + r;
        float f[8];
#pragma unroll
        for (int jj = 0; jj < 8; ++jj) f[jj] = X[base + (long)jj * sld];
        uint4 pkv;
        pkv.x = pk2(f[0], f[1]);
        pkv.y = pk2(f[2], f[3]);
        pkv.z = pk2(f[4], f[5]);
        pkv.w = pk2(f[6], f[7]);
        int s = c ^ (r & 3);
        *reinterpret_cast<uint4*>(Ls + r * 32 + s * 8) = pkv;
    }
}

#define EPI_BF 0   // bf16 C[row][col], ldc
#define EPI_YT 1   // AV: scatter to YtvT[4096][256]
#define EPI_OUT 2  // fp32 out + q + v residual, ldc=4096

// Generic NT MFMA GEMM: C[m][n] = sum_k A[m][k]*B[n][k], tile TM x TN, BK=32.
// DIRECT operands: bf16, element addr = row*ld + (k&kmask) + (k>>kshift)*kpanel.
// TRANS operands: fp32 X, element = X[k*sld + row]  (in-kernel transpose+cast).
template <int TM, int TN, bool TRA, bool TRB, int EPI>
__global__ __launch_bounds__(256) void mm(
    const short* __restrict__ A, const float* __restrict__ Af,
    const short* __restrict__ B, const float* __restrict__ Bf,
    void* __restrict__ C, const float* __restrict__ Rq, const float* __restrict__ Rv,
    int K, int lda, int ldb, int ldc, int kmask, int kshift, long kpanel)
{
    __shared__ __align__(16) short As[TM * 32];
    __shared__ __align__(16) short Bs[TN * 32];

    const int tid = threadIdx.x;
    const int w = tid >> 6, lane = tid & 63;
    const int quad = lane >> 4, l16 = lane & 15;
    const int m0 = blockIdx.y * TM;
    const int n0 = blockIdx.x * TN;

    constexpr int WM = TM / 2;      // wave rows
    constexpr int MT = WM / 16;     // mfma tiles per wave (rows)
    const int wm = (w & 1) * WM;
    const int wn = (w >> 1) * 64;

    f32x4 acc[MT][4];
#pragma unroll
    for (int i = 0; i < MT; ++i)
#pragma unroll
        for (int j = 0; j < 4; ++j) acc[i][j] = (f32x4){0.f, 0.f, 0.f, 0.f};

    for (int k0 = 0; k0 < K; k0 += 32) {
        __syncthreads();
        long koff = (long)(k0 & kmask) + (long)(k0 >> kshift) * kpanel;
        if constexpr (TRA) stage_trans<TM>(Af, lda, m0, k0, As);
        else               stage_direct<TM>(A, lda, m0, koff, As);
        if constexpr (TRB) stage_trans<TN>(Bf, ldb, n0, k0, Bs);
        else               stage_direct<TN>(B, ldb, n0, koff, Bs);
        __syncthreads();

        short8 af[MT], bfr[4];
#pragma unroll
        for (int mt = 0; mt < MT; ++mt) {
            int r = wm + mt * 16 + l16;
            int s = quad ^ (r & 3);
            af[mt] = *reinterpret_cast<const short8*>(&As[r * 32 + s * 8]);
        }
#pragma unroll
        for (int nt = 0; nt < 4; ++nt) {
            int r = wn + nt * 16 + l16;
            int s = quad ^ (r & 3);
            bfr[nt] = *reinterpret_cast<const short8*>(&Bs[r * 32 + s * 8]);
        }
#pragma unroll
        for (int mt = 0; mt < MT; ++mt)
#pragma unroll
            for (int nt = 0; nt < 4; ++nt)
                acc[mt][nt] = __builtin_amdgcn_mfma_f32_16x16x32_bf16(
                    af[mt], bfr[nt], acc[mt][nt], 0, 0, 0);
    }

    // Epilogue. C/D layout: col = lane&15, row = quad*4 + reg.
#pragma unroll
    for (int mt = 0; mt < MT; ++mt)
#pragma unroll
        for (int nt = 0; nt < 4; ++nt)
#pragma unroll
            for (int reg = 0; reg < 4; ++reg) {
                int gr = m0 + wm + mt * 16 + quad * 4 + reg;
                int gc = n0 + wn + nt * 16 + l16;
                float vacc = acc[mt][nt][reg];
                if constexpr (EPI == EPI_BF) {
                    ((short*)C)[(long)gr * ldc + gc] = (short)f2bf(vacc);
                } else if constexpr (EPI == EPI_YT) {
                    long a = (long)gc * 256 + (long)(gr & 1) * 524288 + (gr >> 1);
                    ((short*)C)[a] = (short)f2bf(vacc);
                } else {
                    long a = (long)gr * 4096 + gc;
                    ((float*)C)[a] = vacc + Rq[a] + Rv[a];
                }
            }
}

// Row softmax of T[2048][2048] bf16 in place (one block per row).
__global__ __launch_bounds__(256) void softmax_row(short* __restrict__ T) {
    const int row = blockIdx.x;
    const int tid = threadIdx.x;
    const int w = tid >> 6, lane = tid & 63;
    __shared__ float red[8];

    uint4 u = *reinterpret_cast<const uint4*>(&T[(long)row * 2048 + tid * 8]);
    float f[8];
    f[0] = bf2f((unsigned short)(u.x & 0xffff)); f[1] = bf2f((unsigned short)(u.x >> 16));
    f[2] = bf2f((unsigned short)(u.y & 0xffff)); f[3] = bf2f((unsigned short)(u.y >> 16));
    f[4] = bf2f((unsigned short)(u.z & 0xffff)); f[5] = bf2f((unsigned short)(u.z >> 16));
    f[6] = bf2f((unsigned short)(u.w & 0xffff)); f[7] = bf2f((unsigned short)(u.w >> 16));

    float m = f[0];
#pragma unroll
    for (int j = 1; j < 8; ++j) m = fmaxf(m, f[j]);
    for (int o = 32; o > 0; o >>= 1) m = fmaxf(m, __shfl_down(m, o));
    if (lane == 0) red[w] = m;
    __syncthreads();
    float M = fmaxf(fmaxf(red[0], red[1]), fmaxf(red[2], red[3]));

    float e[8], s = 0.f;
#pragma unroll
    for (int j = 0; j < 8; ++j) { e[j] = __expf(f[j] - M); s += e[j]; }
    for (int o = 32; o > 0; o >>= 1) s += __shfl_down(s, o);
    if (lane == 0) red[4 + w] = s;
    __syncthreads();
    float invL = 1.0f / (red[4] + red[5] + red[6] + red[7]);

    uint4 ov;
    ov.x = pk2(e[0] * invL, e[1] * invL);
    ov.y = pk2(e[2] * invL, e[3] * invL);
    ov.z = pk2(e[4] * invL, e[5] * invL);
    ov.w = pk2(e[6] * invL, e[7] * invL);
    *reinterpret_cast<uint4*>(&T[(long)row * 2048 + tid * 8]) = ov;
}

// Cast 4 weight matrices (131072 fp32 each) to bf16, concatenated into W.
__global__ __launch_bounds__(256) void cast_w(
    const float* __restrict__ a, const float* __restrict__ b,
    const float* __restrict__ c, const float* __restrict__ d,
    short* __restrict__ W)
{
    const float* S[4] = {a, b, c, d};
    int sel = blockIdx.y;
    int i = (blockIdx.x * 256 + threadIdx.x) * 4;
    float4 f = *reinterpret_cast<const float4*>(&S[sel][i]);
    uint2 o;
    o.x = pk2(f.x, f.y);
    o.y = pk2(f.z, f.w);
    *reinterpret_cast<uint2*>(&W[sel * 131072 + i]) = o;
}

extern "C" void kernel_launch(void* const* d_in, const int* in_sizes, int n_in,
                              void* d_out, int out_size, void* d_ws, size_t ws_size,
                              hipStream_t stream)
{
    const float* q    = (const float*)d_in[0];
    const float* kk   = (const float*)d_in[1];
    const float* v    = (const float*)d_in[2];
    const float* Wphi = (const float*)d_in[3];
    const float* Wth  = (const float*)d_in[4];
    const float* Wg   = (const float*)d_in[5];
    const float* Wm   = (const float*)d_in[6];
    float* out = (float*)d_out;
    dim3 blk(256);

    // Workspace (shorts): Wb 512K | Phi 1M | Th 1M | Gr 1M | T 4M | YtvT 1M  = 17 MB
    short* Wb   = (short*)d_ws;
    short* Phi  = Wb + 524288;       // [4096][256] = phi^T (conv-T output)
    short* Th   = Phi + 1048576;     // [4096][256]
    short* Gr   = Th + 1048576;      // [256][4096] (flat == G[512][2048])
    short* T    = Gr + 1048576;      // [2048][2048] = S^T, then softmaxed attn^T
    short* YtvT = T + 4194304;       // [4096][256]
    const short* WbPhi = Wb;
    const short* WbTh  = Wb + 131072;
    const short* WbG   = Wb + 262144;
    const short* WbM   = Wb + 393216;

    const int LIN_M = 0x3FFFFFFF, LIN_S = 30;  // linear k addressing

    cast_w<<<dim3(128, 4), blk, 0, stream>>>(Wphi, Wth, Wg, Wm, Wb);

    for (int b = 0; b < 8; ++b) {
        const float* qb = q + b * QS;
        const float* kb = kk + b * QS;
        const float* vb = v + b * QS;

        // conv-T: Phi[p][o] = sum_c q[c][p] * Wphi[o][c]   (M=4096, N=256, K=512)
        mm<128, 128, true, false, EPI_BF><<<dim3(2, 32), blk, 0, stream>>>(
            nullptr, qb, WbPhi, nullptr, Phi, nullptr, nullptr,
            512, 4096, 512, 256, LIN_M, LIN_S, 0);
        mm<128, 128, true, false, EPI_BF><<<dim3(2, 32), blk, 0, stream>>>(
            nullptr, kb, WbTh, nullptr, Th, nullptr, nullptr,
            512, 4096, 512, 256, LIN_M, LIN_S, 0);
        // conv-N: Gr[o][p] = sum_c Wg[o][c] * v[c][p]      (M=256, N=4096, K=512)
        mm<128, 128, false, true, EPI_BF><<<dim3(32, 2), blk, 0, stream>>>(
            WbG, nullptr, nullptr, vb, Gr, nullptr, nullptr,
            512, 512, 4096, 4096, LIN_M, LIN_S, 0);

        // score: T[m][n] = S^T = sum_{h,o} Phi[h*2048+m][o]*Th[h*2048+n][o]
        // k-panel: kmask=255, kshift=8, kpanel=2048*256  (M=N=2048, K=512)
        mm<128, 128, false, false, EPI_BF><<<dim3(16, 16), blk, 0, stream>>>(
            Phi, nullptr, Th, nullptr, T, nullptr, nullptr,
            512, 256, 256, 2048, 255, 8, 524288);

        softmax_row<<<dim3(2048), blk, 0, stream>>>(T);

        // AV: Yt[c'][m] = sum_n Gflat[c'][n] * T[m][n]  (M=512, N=2048, K=2048)
        // epilogue scatters to YtvT[4096][256]
        mm<64, 128, false, false, EPI_YT><<<dim3(16, 8), blk, 0, stream>>>(
            Gr, nullptr, T, nullptr, YtvT, nullptr, nullptr,
            2048, 2048, 2048, 256, LIN_M, LIN_S, 0);

        // mask + residual: out[o][p] = sum_i WbM[o][i]*YtvT[p][i] + q + v
        // (M=512, N=4096, K=256)
        mm<128, 128, false, false, EPI_OUT><<<dim3(32, 4), blk, 0, stream>>>(
            WbM, nullptr, YtvT, nullptr, out + b * QS, qb, vb,
            256, 256, 256, 4096, LIN_M, LIN_S, 0);
    }
}